// Round 3
// baseline (226.067 us; speedup 1.0000x reference)
//
#include <hip/hip_runtime.h>

// SLAYER 3-layer CUBA SNN — i8 3-plane MFMA GEMM + fused leaky-IF scan.
// R22: T14 async-STAGE split on the R19 structure. R19's stall model: glds16
// issued ~0 cyc before the __syncthreads vmcnt(0) drain -> ~2900 cyc/step of
// exposed L2 return (35% of wall). R20/R21 (kc=64 counted-vmcnt dbuf) fixed
// the drain but doubled barrier count -> net loss (60.1 us vs R19 54.6).
// R22 keeps R19's shape exactly (kc=128, 16 phases, single 40 KB LDS buffer,
// 4 blocks/CU, 2 syncthreads/phase) and swaps glds16 for reg-staging:
//   top of phase k: 5x global_load_dwordx4 -> nxt[] (tile k+1), sched_barrier
//   compute k (14 ds_read_b128 + 24 MFMA)
//   __syncthreads()          // vmcnt(0) drain is FREE: nxt landed ~4k cyc ago
//   5x ds_write_b128 nxt -> LDS (swizzled addr; global side now linear)
//   __syncthreads()
// Same LDS-write bytes as glds16 DMA; +20 VGPR (48->~80, still 8 waves/SIMD).
// Swizzle = R19's proven 8-unit form: phys = row*8 + (u ^ (row&7)) (262K
// residual conflicts = 2-way free); applied on ds_write + frag-read sides.
// Unchanged from R19 (214.2 us, absmax 0.0): i8 3-plane weights
// (W = 2^-8*q1 + 2^-15*q2 + 2^-22*q3, exact), mfma_i32_16x16x64_i8 frag
// geometry fr=lane&15 q=lane>>4, 512-thr 128m x 64o tiles, XCD-aware remap,
// fused leaky-IF scan epilogue, prep / gemm3_scan kernels.

typedef unsigned short ushort_t;
typedef unsigned int uint_t;
typedef unsigned char uchar_t;
typedef int i32x4 __attribute__((ext_vector_type(4)));

#define S1F 0.00390625f             // 2^-8
#define S2F 3.0517578125e-5f        // 2^-15
#define S3F 2.384185791015625e-7f   // 2^-22

// ---- prep: W1/W2 -> 3 i8 planes (blocks 0..3071) + spike transpose ---------
__global__ __launch_bounds__(256) void prep(const float* __restrict__ W1,
                                            const float* __restrict__ W2,
                                            const float* __restrict__ spike,
                                            char* __restrict__ w1q1,
                                            char* __restrict__ w1q2,
                                            char* __restrict__ w1q3,
                                            char* __restrict__ w2q1,
                                            char* __restrict__ w2q2,
                                            char* __restrict__ w2q3,
                                            uchar_t* __restrict__ A1) {
  const int tid = threadIdx.x;
  if (blockIdx.x < 3072) {
    const float* W;
    char *p1, *p2, *p3;
    size_t e0;
    if (blockIdx.x < 2048) {
      W = W1; p1 = w1q1; p2 = w1q2; p3 = w1q3;
      e0 = (size_t)blockIdx.x * 1024 + tid * 4;
    } else {
      W = W2; p1 = w2q1; p2 = w2q2; p3 = w2q3;
      e0 = (size_t)(blockIdx.x - 2048) * 1024 + tid * 4;
    }
    float4 w = *(const float4*)(W + e0);
    char4 c1, c2, c3;
    float q, r;
#define QUANT(comp, f1, f2, f3)                    \
    q = rintf((comp) * 256.0f);  f1 = (char)(int)q; \
    r = (comp) - q * S1F;                           \
    q = rintf(r * 32768.0f);     f2 = (char)(int)q; \
    r = r - q * S2F;                                \
    q = rintf(r * 4194304.0f);   f3 = (char)(int)q;
    QUANT(w.x, c1.x, c2.x, c3.x)
    QUANT(w.y, c1.y, c2.y, c3.y)
    QUANT(w.z, c1.z, c2.z, c3.z)
    QUANT(w.w, c1.w, c2.w, c3.w)
#undef QUANT
    *(char4*)(p1 + e0) = c1;
    *(char4*)(p2 + e0) = c2;
    *(char4*)(p3 + e0) = c3;
    return;
  }
  // spike [b][i][t] f32 -> A1 [b*128+t][i] i8 (0/1)
  __shared__ uchar_t lds8[128 * 132];  // [i][t] padded
  const int bid = blockIdx.x - 3072;   // 0..1023
  const int b = bid >> 4;
  const int i0 = (bid & 15) * 128;
#pragma unroll
  for (int it = 0; it < 16; ++it) {
    int p = it * 256 + tid;
    int i = p >> 5, tg = (p & 31) * 4;
    float4 v = *(const float4*)(spike + ((size_t)b * 2048 + i0 + i) * 128 + tg);
    uint_t pk = (v.x != 0.0f ? 1u : 0u) | (v.y != 0.0f ? 1u : 0u) << 8 |
                (v.z != 0.0f ? 1u : 0u) << 16 | (v.w != 0.0f ? 1u : 0u) << 24;
    *(uint_t*)(lds8 + i * 132 + tg) = pk;
  }
  __syncthreads();
#pragma unroll
  for (int it = 0; it < 16; ++it) {
    int p = it * 256 + tid;
    int t = p >> 5, jw = p & 31;  // output uint (4 i-bytes)
    uint_t u = (uint_t)lds8[(4 * jw + 0) * 132 + t] |
               ((uint_t)lds8[(4 * jw + 1) * 132 + t] << 8) |
               ((uint_t)lds8[(4 * jw + 2) * 132 + t] << 16) |
               ((uint_t)lds8[(4 * jw + 3) * 132 + t] << 24);
    *(uint_t*)(A1 + (size_t)(b * 128 + t) * 2048 + i0 + jw * 4) = u;
  }
}

// ---- fused GEMM (128m x 64o, kc=128, T14 reg-staged, 512 thr) + scan -------
__global__ __launch_bounds__(512, 4)
void gemm_scan(const uchar_t* __restrict__ A, const char* __restrict__ Q1,
               const char* __restrict__ Q2, const char* __restrict__ Q3,
               uchar_t* __restrict__ S, int K) {
  __shared__ float smemf[10240];     // 40,960 B staging; Zt overlay 33,280 B
  uchar_t* sA = (uchar_t*)smemf;     // A: slots 0..1023; B plane p: 1024+p*512
  float* Zt = smemf;                 // [128 t][65] epilogue overlay

  const int tid = threadIdx.x;
  const int wave = tid >> 6, lane = tid & 63;
  // XCD-aware remap (grid 16 x 64): XCD ~= bx%8 owns b-tiles [8c, 8c+8)
  const int bt = (blockIdx.x & 7) * 8 + (blockIdx.y & 7);          // 0..63
  const int ot = (blockIdx.x >> 3) * 8 + (blockIdx.y >> 3);        // 0..15
  const int m0 = bt * 128;
  const int o0 = ot * 64;
  const int qm = wave >> 2, qn = wave & 3;
  const int fr = lane & 15, q = lane >> 4;

  i32x4 acc[4][3];
#pragma unroll
  for (int i = 0; i < 4; ++i)
#pragma unroll
    for (int p = 0; p < 3; ++p) acc[i][p] = (i32x4){0, 0, 0, 0};

  // staging: 2560 slots of 16 B, 5 rounds of 512 threads. Global side is
  // LINEAR (coalesced); swizzle applied on the ds_write address.
  const char* qplanes[3] = {Q1, Q2, Q3};
  const uchar_t* gsrc[5];
  uchar_t* ldst[5];
#pragma unroll
  for (int it = 0; it < 5; ++it) {
    int s = it * 512 + tid;
    int row, u, lbase;
    const uchar_t* base;
    if (s < 1024) {
      row = s >> 3; u = s & 7; lbase = 0;
      base = A + (size_t)(m0 + row) * K;
    } else {
      int t2 = s - 1024;
      int p = t2 >> 9, w = t2 & 511;
      row = w >> 3; u = w & 7; lbase = 1024 + p * 512;
      base = (const uchar_t*)qplanes[p] + (size_t)(o0 + row) * K;
    }
    gsrc[it] = base + u * 16;
    ldst[it] = sA + (size_t)(lbase + row * 8 + (u ^ (row & 7))) * 16;
  }

  // frag LDS byte offsets per k-half hh: logical unit = hh*4 + q
  int aoff[4][2], boff[3][2];
#pragma unroll
  for (int i = 0; i < 4; ++i) {
    int row = qm * 64 + i * 16 + fr;
#pragma unroll
    for (int hh = 0; hh < 2; ++hh)
      aoff[i][hh] = (row * 8 + ((hh * 4 + q) ^ (row & 7))) * 16;
  }
  {
    int row = qn * 16 + fr;
#pragma unroll
    for (int hh = 0; hh < 2; ++hh) {
      int rel = row * 8 + ((hh * 4 + q) ^ (row & 7));
#pragma unroll
      for (int p = 0; p < 3; ++p)
        boff[p][hh] = (1024 + p * 512 + rel) * 16;
    }
  }

  auto compute = [&]() {
#pragma unroll
    for (int hh = 0; hh < 2; ++hh) {
      i32x4 af[4], bq[3];
#pragma unroll
      for (int i = 0; i < 4; ++i) af[i] = *(const i32x4*)(sA + aoff[i][hh]);
#pragma unroll
      for (int p = 0; p < 3; ++p) bq[p] = *(const i32x4*)(sA + boff[p][hh]);
#pragma unroll
      for (int p = 0; p < 3; ++p)
#pragma unroll
        for (int i = 0; i < 4; ++i)
          acc[i][p] = __builtin_amdgcn_mfma_i32_16x16x64_i8(af[i], bq[p],
                                                            acc[i][p], 0, 0, 0);
    }
  };

  // prologue: stage tile 0 (exposed once, ~L2 latency)
  {
    i32x4 st[5];
#pragma unroll
    for (int it = 0; it < 5; ++it) st[it] = *(const i32x4*)(gsrc[it]);
#pragma unroll
    for (int it = 0; it < 5; ++it) *(i32x4*)(ldst[it]) = st[it];
  }
  __syncthreads();

  for (int kc = 0; kc + 128 < K; kc += 128) {
    // issue tile-(k+1) loads FIRST: full compute phase of latency lead
    i32x4 nxt[5];
#pragma unroll
    for (int it = 0; it < 5; ++it)
      nxt[it] = *(const i32x4*)(gsrc[it] + kc + 128);
    __builtin_amdgcn_sched_barrier(0);  // pin issue-early (loads stay above)

    compute();                           // tile k from LDS

    __syncthreads();                     // reads done; vmcnt drain free
#pragma unroll
    for (int it = 0; it < 5; ++it) *(i32x4*)(ldst[it]) = nxt[it];
    __syncthreads();                     // LDS refilled with tile k+1
  }
  compute();                             // last tile
  __syncthreads();                       // all reads done before Zt overlay

  // combine planes -> fp32, write Z-tile (C/D: col=fr, row=q*4+rr)
#pragma unroll
  for (int i = 0; i < 4; ++i)
#pragma unroll
    for (int rr = 0; rr < 4; ++rr) {
      int t = qm * 64 + i * 16 + q * 4 + rr;
      float z = (float)acc[i][0][rr] * S1F + (float)acc[i][1][rr] * S2F +
                (float)acc[i][2][rr] * S3F;
      Zt[t * 65 + qn * 16 + fr] = z;
    }
  __syncthreads();

  // fused leaky-IF scan: thread tid<64 owns o-column (o0+tid)
  if (tid < 64) {
#pragma clang fp contract(off)
    float cur = 0.0f, vol = 0.0f;
    const int o = o0 + tid;
    for (int t = 0; t < 128; ++t) {
      float z = Zt[t * 65 + tid];
      cur = cur * 0.7f;
      cur = cur + z;
      vol = vol * 0.2f;
      vol = vol + cur;
      float v = vol - 1.0f;
      float s = (v >= 0.0f) ? 1.0f : 0.0f;
      vol = vol * (1.0f - s);
      S[(size_t)(m0 + t) * 1024 + o] = (v >= 0.0f) ? 1u : 0u;
    }
  }
}

// ---------- layer 3 fused: per-b dense (O=2, fp32) + scan + output ----------
__global__ __launch_bounds__(256) void gemm3_scan(const uchar_t* __restrict__ X,
                                                  const float* __restrict__ W3,
                                                  float* __restrict__ out) {
  __shared__ float w3s[2048];
  __shared__ float z3[256];  // [t*2 + o]
  __shared__ float sp[256];  // [o*128 + t]
  const int tid = threadIdx.x;
  const int b = blockIdx.x;
  for (int i = tid; i < 2048; i += 256) w3s[i] = W3[i];
  __syncthreads();
  const int wave = tid >> 6, lane = tid & 63;
  for (int tt = 0; tt < 32; ++tt) {
    int t = wave * 32 + tt;
    const uint4* rp = (const uint4*)(X + (size_t)(b * 128 + t) * 1024);
    uint4 v = rp[lane];
    float s0 = 0.0f, s1 = 0.0f;
    const uint_t uw[4] = {v.x, v.y, v.z, v.w};
#pragma unroll
    for (int wq = 0; wq < 4; ++wq)
#pragma unroll
      for (int c = 0; c < 4; ++c) {
        float x = (float)((uw[wq] >> (8 * c)) & 1u);
        int i0 = lane * 16 + wq * 4 + c;
        s0 = fmaf(x, w3s[i0], s0);
        s1 = fmaf(x, w3s[1024 + i0], s1);
      }
#pragma unroll
    for (int off = 32; off > 0; off >>= 1) {
      s0 += __shfl_down(s0, off);
      s1 += __shfl_down(s1, off);
    }
    if (lane == 0) {
      z3[t * 2] = s0;
      z3[t * 2 + 1] = s1;
    }
  }
  __syncthreads();
  if (tid < 2) {
#pragma clang fp contract(off)
    float cur = 0.0f, vol = 0.0f;
    for (int t = 0; t < 128; ++t) {
      float z = z3[t * 2 + tid];
      cur = cur * 0.7f;
      cur = cur + z;
      vol = vol * 0.2f;
      vol = vol + cur;
      float v = vol - 1.0f;
      float s = (v >= 0.0f) ? 1.0f : 0.0f;
      vol = vol * (1.0f - s);
      sp[tid * 128 + t] = s;
    }
  }
  __syncthreads();
  out[b * 256 + tid] = sp[tid];
}

extern "C" void kernel_launch(void* const* d_in, const int* in_sizes, int n_in,
                              void* d_out, int out_size, void* d_ws, size_t ws_size,
                              hipStream_t stream) {
  const float* spike = (const float*)d_in[0];  // [64, 2048, 128]
  const float* W1 = (const float*)d_in[1];     // [1024, 2048]
  const float* W2 = (const float*)d_in[2];     // [1024, 1024]
  const float* W3 = (const float*)d_in[3];     // [2, 1024]
  float* out = (float*)d_out;                  // [64, 2, 128]

  char* ws = (char*)d_ws;
  const size_t MB = 1024 * 1024;
  uchar_t* A1 = (uchar_t*)ws;                  // 16 MB [8192][2048] i8
  uchar_t* S2 = (uchar_t*)(ws + 16 * MB);      // 8 MB  [8192][1024] i8
  uchar_t* S3 = (uchar_t*)(ws + 24 * MB);      // 8 MB
  char* w1q1 = ws + 32 * MB;                   // 2 MB each
  char* w1q2 = ws + 34 * MB;
  char* w1q3 = ws + 36 * MB;
  char* w2q1 = ws + 38 * MB;                   // 1 MB each
  char* w2q2 = ws + 39 * MB;
  char* w2q3 = ws + 40 * MB;

  // blocks 0..2047: W1 quant; 2048..3071: W2 quant; 3072..4095: transpose
  prep<<<4096, 256, 0, stream>>>(W1, W2, spike, w1q1, w1q2, w1q3, w2q1, w2q2,
                                 w2q3, A1);
  // L1: M=8192 (b*128+t), K=2048 B, O=1024 (16 o-tiles of 64), XCD-remapped
  gemm_scan<<<dim3(16, 64), 512, 0, stream>>>(A1, w1q1, w1q2, w1q3, S2, 2048);
  // L2: K=1024 B, XCD-remapped
  gemm_scan<<<dim3(16, 64), 512, 0, stream>>>(S2, w2q1, w2q2, w2q3, S3, 1024);
  // L3 + final scan + output
  gemm3_scan<<<64, 256, 0, stream>>>(S3, W3, out);
}

// Round 4
// 213.743 us; speedup vs baseline: 1.0577x; 1.0577x over previous
//
#include <hip/hip_runtime.h>

// SLAYER 3-layer CUBA SNN — i8 3-plane MFMA GEMM + fused leaky-IF scan.
// R23 = R19 verbatim restoration (best: 214.6 us, absmax 0.0).
// Structural post-mortem of R20-R22 (all regressed, 60-63 us L1 vs 54.6):
//  - R20 kc=64 counted-vmcnt dbuf: doubled barrier count ate the gain; also
//    16-bank swizzle -> 4-way conflicts (7.6M).
//  - R21 fixed conflicts (262K) but kept 2x barriers: 60.1 us.
//  - R22 T14 reg-staging (load->reg early, ds_write late): 62.7 us — ds_write
//    round-trip + syncthreads convoy cost more than the drain it hid.
// Conclusion: this kernel sits at the 2-barrier 128-tile structure ceiling
// (guide: m97-class; implicit 4-block/CU wave overlap already covers the
// staging drain; source-level pipelining adds only overhead). Resource model
// at 54.6 us: LDS-read ~43%, MFMA ~45%/4 pipes, L2-fill ~35% — multi-resource
// saturated under barrier convoy, not single-pipe bound.
// FINAL CONFIG:
// - i8 3-plane weights: W = 2^-8*q1 + 2^-15*q2 + 2^-22*q3 (exact fp32
//   residuals, per-weight err <= 2^-23); spikes exact in i8; i32 MFMA accum
//   exact -> absmax 0.0 across R12-R19.
// - mfma_i32_16x16x64_i8, frag geometry fr=lane&15, q=lane>>4 (conflict-free),
//   slot swizzle phys = row*8 + (u0 ^ (row&7)).
// - 512-thr blocks, 128m x 64o tile, kc=128B, stage->barrier->MFMA->barrier.
// - XCD-aware remap: bt=(bx&7)*8+(by&7), ot=(bx>>3)*8+(by>>3) -> each XCD
//   owns 2 MB of A (L2-resident; FETCH 72->41 MB, L1 68->53 us).
// - Fused leaky-IF scan epilogue (m = b*128 + t layout), fused L3+scan.

typedef unsigned short ushort_t;
typedef unsigned int uint_t;
typedef unsigned char uchar_t;
typedef int i32x4 __attribute__((ext_vector_type(4)));

#define S1F 0.00390625f             // 2^-8
#define S2F 3.0517578125e-5f        // 2^-15
#define S3F 2.384185791015625e-7f   // 2^-22

__device__ __forceinline__ void glds16(const uchar_t* g, uchar_t* l) {
  __builtin_amdgcn_global_load_lds(
      (const __attribute__((address_space(1))) uint_t*)g,
      (__attribute__((address_space(3))) uint_t*)l, 16, 0, 0);
}

// ---- prep: W1/W2 -> 3 i8 planes (blocks 0..3071) + spike transpose ---------
__global__ __launch_bounds__(256) void prep(const float* __restrict__ W1,
                                            const float* __restrict__ W2,
                                            const float* __restrict__ spike,
                                            char* __restrict__ w1q1,
                                            char* __restrict__ w1q2,
                                            char* __restrict__ w1q3,
                                            char* __restrict__ w2q1,
                                            char* __restrict__ w2q2,
                                            char* __restrict__ w2q3,
                                            uchar_t* __restrict__ A1) {
  const int tid = threadIdx.x;
  if (blockIdx.x < 3072) {
    const float* W;
    char *p1, *p2, *p3;
    size_t e0;
    if (blockIdx.x < 2048) {
      W = W1; p1 = w1q1; p2 = w1q2; p3 = w1q3;
      e0 = (size_t)blockIdx.x * 1024 + tid * 4;
    } else {
      W = W2; p1 = w2q1; p2 = w2q2; p3 = w2q3;
      e0 = (size_t)(blockIdx.x - 2048) * 1024 + tid * 4;
    }
    float4 w = *(const float4*)(W + e0);
    char4 c1, c2, c3;
    float q, r;
#define QUANT(comp, f1, f2, f3)                    \
    q = rintf((comp) * 256.0f);  f1 = (char)(int)q; \
    r = (comp) - q * S1F;                           \
    q = rintf(r * 32768.0f);     f2 = (char)(int)q; \
    r = r - q * S2F;                                \
    q = rintf(r * 4194304.0f);   f3 = (char)(int)q;
    QUANT(w.x, c1.x, c2.x, c3.x)
    QUANT(w.y, c1.y, c2.y, c3.y)
    QUANT(w.z, c1.z, c2.z, c3.z)
    QUANT(w.w, c1.w, c2.w, c3.w)
#undef QUANT
    *(char4*)(p1 + e0) = c1;
    *(char4*)(p2 + e0) = c2;
    *(char4*)(p3 + e0) = c3;
    return;
  }
  // spike [b][i][t] f32 -> A1 [b*128+t][i] i8 (0/1)
  __shared__ uchar_t lds8[128 * 132];  // [i][t] padded
  const int bid = blockIdx.x - 3072;   // 0..1023
  const int b = bid >> 4;
  const int i0 = (bid & 15) * 128;
#pragma unroll
  for (int it = 0; it < 16; ++it) {
    int p = it * 256 + tid;
    int i = p >> 5, tg = (p & 31) * 4;
    float4 v = *(const float4*)(spike + ((size_t)b * 2048 + i0 + i) * 128 + tg);
    uint_t pk = (v.x != 0.0f ? 1u : 0u) | (v.y != 0.0f ? 1u : 0u) << 8 |
                (v.z != 0.0f ? 1u : 0u) << 16 | (v.w != 0.0f ? 1u : 0u) << 24;
    *(uint_t*)(lds8 + i * 132 + tg) = pk;
  }
  __syncthreads();
#pragma unroll
  for (int it = 0; it < 16; ++it) {
    int p = it * 256 + tid;
    int t = p >> 5, jw = p & 31;  // output uint (4 i-bytes)
    uint_t u = (uint_t)lds8[(4 * jw + 0) * 132 + t] |
               ((uint_t)lds8[(4 * jw + 1) * 132 + t] << 8) |
               ((uint_t)lds8[(4 * jw + 2) * 132 + t] << 16) |
               ((uint_t)lds8[(4 * jw + 3) * 132 + t] << 24);
    *(uint_t*)(A1 + (size_t)(b * 128 + t) * 2048 + i0 + jw * 4) = u;
  }
}

// ---- fused GEMM (128m x 64o, kc=128B, 512 thr, i8 3-plane) + scan ----------
// XCD-aware tile assignment: see header comment.
__global__ __launch_bounds__(512, 4)
void gemm_scan(const uchar_t* __restrict__ A, const char* __restrict__ Q1,
               const char* __restrict__ Q2, const char* __restrict__ Q3,
               uchar_t* __restrict__ S, int K) {
  __shared__ float smemf[10240];     // 40,960 B staging; Zt overlay 33,280 B
  uchar_t* sA = (uchar_t*)smemf;     // A: slots 0..1023; B plane p: 1024+p*512
  float* Zt = smemf;                 // [128 t][65] epilogue overlay

  const int tid = threadIdx.x;
  const int wave = tid >> 6, lane = tid & 63;
  // XCD-aware remap (grid 16 x 64): XCD ~= bx%8 owns b-tiles [8c, 8c+8)
  const int bt = (blockIdx.x & 7) * 8 + (blockIdx.y & 7);          // 0..63
  const int ot = (blockIdx.x >> 3) * 8 + (blockIdx.y >> 3);        // 0..15
  const int m0 = bt * 128;
  const int o0 = ot * 64;
  const int qm = wave >> 2, qn = wave & 3;
  const int fr = lane & 15, q = lane >> 4;

  i32x4 acc[4][3];
#pragma unroll
  for (int i = 0; i < 4; ++i)
#pragma unroll
    for (int p = 0; p < 3; ++p) acc[i][p] = (i32x4){0, 0, 0, 0};

  // staging: 2560 slots (A 1024 + B 3x512), exactly 5 rounds of 512 threads.
  const char* qplanes[3] = {Q1, Q2, Q3};
  const uchar_t* gsrc[5];
  uchar_t* ldst[5];
#pragma unroll
  for (int it = 0; it < 5; ++it) {
    int s = it * 512 + tid;
    ldst[it] = sA + (size_t)(it * 512 + wave * 64) * 16;
    if (s < 1024) {
      int row = s >> 3;
      int u0 = (s & 7) ^ (row & 7);
      gsrc[it] = A + (size_t)(m0 + row) * K + u0 * 16;
    } else {
      int t2 = s - 1024;
      int p = t2 >> 9, w = t2 & 511;
      int row = w >> 3;
      int u0 = (w & 7) ^ (row & 7);
      gsrc[it] = (const uchar_t*)qplanes[p] + (size_t)(o0 + row) * K + u0 * 16;
    }
  }

  // frag LDS byte offsets per k-half hh: u0 = hh*4 + q
  int aoff[4][2], boff[3][2];  // [p][hh]
#pragma unroll
  for (int i = 0; i < 4; ++i) {
    int row = qm * 64 + i * 16 + fr;
#pragma unroll
    for (int hh = 0; hh < 2; ++hh)
      aoff[i][hh] = (row * 8 + ((hh * 4 + q) ^ (row & 7))) * 16;
  }
  {
    int row = qn * 16 + fr;
#pragma unroll
    for (int hh = 0; hh < 2; ++hh) {
      int rel = row * 8 + ((hh * 4 + q) ^ (row & 7));
#pragma unroll
      for (int p = 0; p < 3; ++p)
        boff[p][hh] = (1024 + p * 512 + rel) * 16;
    }
  }

  for (int kc = 0; kc < K; kc += 128) {
#pragma unroll
    for (int it = 0; it < 5; ++it) glds16(gsrc[it] + kc, ldst[it]);
    __syncthreads();

#pragma unroll
    for (int hh = 0; hh < 2; ++hh) {
      i32x4 af[4], bq[3];
#pragma unroll
      for (int i = 0; i < 4; ++i) af[i] = *(const i32x4*)(sA + aoff[i][hh]);
#pragma unroll
      for (int p = 0; p < 3; ++p) bq[p] = *(const i32x4*)(sA + boff[p][hh]);
#pragma unroll
      for (int p = 0; p < 3; ++p)
#pragma unroll
        for (int i = 0; i < 4; ++i)
          acc[i][p] = __builtin_amdgcn_mfma_i32_16x16x64_i8(af[i], bq[p], acc[i][p], 0, 0, 0);
    }
    __syncthreads();
  }

  // combine planes -> fp32, write Z-tile (C/D: col=fr, row=q*4+rr)
#pragma unroll
  for (int i = 0; i < 4; ++i)
#pragma unroll
    for (int rr = 0; rr < 4; ++rr) {
      int t = qm * 64 + i * 16 + q * 4 + rr;
      float z = (float)acc[i][0][rr] * S1F + (float)acc[i][1][rr] * S2F +
                (float)acc[i][2][rr] * S3F;
      Zt[t * 65 + qn * 16 + fr] = z;
    }
  __syncthreads();

  // fused leaky-IF scan: thread tid<64 owns o-column (o0+tid)
  if (tid < 64) {
#pragma clang fp contract(off)
    float cur = 0.0f, vol = 0.0f;
    const int o = o0 + tid;
    for (int t = 0; t < 128; ++t) {
      float z = Zt[t * 65 + tid];
      cur = cur * 0.7f;
      cur = cur + z;
      vol = vol * 0.2f;
      vol = vol + cur;
      float v = vol - 1.0f;
      float s = (v >= 0.0f) ? 1.0f : 0.0f;
      vol = vol * (1.0f - s);
      S[(size_t)(m0 + t) * 1024 + o] = (v >= 0.0f) ? 1u : 0u;
    }
  }
}

// ---------- layer 3 fused: per-b dense (O=2, fp32) + scan + output ----------
__global__ __launch_bounds__(256) void gemm3_scan(const uchar_t* __restrict__ X,
                                                  const float* __restrict__ W3,
                                                  float* __restrict__ out) {
  __shared__ float w3s[2048];
  __shared__ float z3[256];  // [t*2 + o]
  __shared__ float sp[256];  // [o*128 + t]
  const int tid = threadIdx.x;
  const int b = blockIdx.x;
  for (int i = tid; i < 2048; i += 256) w3s[i] = W3[i];
  __syncthreads();
  const int wave = tid >> 6, lane = tid & 63;
  for (int tt = 0; tt < 32; ++tt) {
    int t = wave * 32 + tt;
    const uint4* rp = (const uint4*)(X + (size_t)(b * 128 + t) * 1024);
    uint4 v = rp[lane];
    float s0 = 0.0f, s1 = 0.0f;
    const uint_t uw[4] = {v.x, v.y, v.z, v.w};
#pragma unroll
    for (int wq = 0; wq < 4; ++wq)
#pragma unroll
      for (int c = 0; c < 4; ++c) {
        float x = (float)((uw[wq] >> (8 * c)) & 1u);
        int i0 = lane * 16 + wq * 4 + c;
        s0 = fmaf(x, w3s[i0], s0);
        s1 = fmaf(x, w3s[1024 + i0], s1);
      }
#pragma unroll
    for (int off = 32; off > 0; off >>= 1) {
      s0 += __shfl_down(s0, off);
      s1 += __shfl_down(s1, off);
    }
    if (lane == 0) {
      z3[t * 2] = s0;
      z3[t * 2 + 1] = s1;
    }
  }
  __syncthreads();
  if (tid < 2) {
#pragma clang fp contract(off)
    float cur = 0.0f, vol = 0.0f;
    for (int t = 0; t < 128; ++t) {
      float z = z3[t * 2 + tid];
      cur = cur * 0.7f;
      cur = cur + z;
      vol = vol * 0.2f;
      vol = vol + cur;
      float v = vol - 1.0f;
      float s = (v >= 0.0f) ? 1.0f : 0.0f;
      vol = vol * (1.0f - s);
      sp[tid * 128 + t] = s;
    }
  }
  __syncthreads();
  out[b * 256 + tid] = sp[tid];
}

extern "C" void kernel_launch(void* const* d_in, const int* in_sizes, int n_in,
                              void* d_out, int out_size, void* d_ws, size_t ws_size,
                              hipStream_t stream) {
  const float* spike = (const float*)d_in[0];  // [64, 2048, 128]
  const float* W1 = (const float*)d_in[1];     // [1024, 2048]
  const float* W2 = (const float*)d_in[2];     // [1024, 1024]
  const float* W3 = (const float*)d_in[3];     // [2, 1024]
  float* out = (float*)d_out;                  // [64, 2, 128]

  char* ws = (char*)d_ws;
  const size_t MB = 1024 * 1024;
  uchar_t* A1 = (uchar_t*)ws;                  // 16 MB [8192][2048] i8
  uchar_t* S2 = (uchar_t*)(ws + 16 * MB);      // 8 MB  [8192][1024] i8
  uchar_t* S3 = (uchar_t*)(ws + 24 * MB);      // 8 MB
  char* w1q1 = ws + 32 * MB;                   // 2 MB each
  char* w1q2 = ws + 34 * MB;
  char* w1q3 = ws + 36 * MB;
  char* w2q1 = ws + 38 * MB;                   // 1 MB each
  char* w2q2 = ws + 39 * MB;
  char* w2q3 = ws + 40 * MB;

  // blocks 0..2047: W1 quant; 2048..3071: W2 quant; 3072..4095: transpose
  prep<<<4096, 256, 0, stream>>>(W1, W2, spike, w1q1, w1q2, w1q3, w2q1, w2q2,
                                 w2q3, A1);
  // L1: M=8192 (b*128+t), K=2048 B, O=1024 (16 o-tiles of 64), XCD-remapped
  gemm_scan<<<dim3(16, 64), 512, 0, stream>>>(A1, w1q1, w1q2, w1q3, S2, 2048);
  // L2: K=1024 B, XCD-remapped
  gemm_scan<<<dim3(16, 64), 512, 0, stream>>>(S2, w2q1, w2q2, w2q3, S3, 1024);
  // L3 + final scan + output
  gemm3_scan<<<64, 256, 0, stream>>>(S3, W3, out);
}

// Round 6
// 212.740 us; speedup vs baseline: 1.0626x; 1.0047x over previous
//
#include <hip/hip_runtime.h>

// SLAYER 3-layer CUBA SNN — i8 3-plane MFMA GEMM + fused leaky-IF scan.
// R25 = R24 with compile fix (scan3's `#pragma clang fp contract(off)` must
// be at the START of the compound statement, before declarations).
// R24 design: R19 GEMM core (proven best, untouched) + non-GEMM overhaul:
//  (1) L3 fused into L2's gemm_scan epilogue: scan wave __ballot's the 64-o
//      spike mask per t; pass-2 (128 thr) computes per-t partial dots with
//      the block's W3 slice and atomicAdds into z3[2][128][64] (64 KB ws,
//      zeroed by prep). gemm3_scan (64 blocks = 75% of chip idle + 16 MB
//      S3 HBM round-trip) deleted; tiny scan3<<<1,128>>> does the final
//      128 leaky-IF scans. L1/L2 z-paths bit-identical to R19; only L3's
//      fp32 summation order changes (~1e-7 vs empirical margin >~1e-4).
//  (2) prep transpose LDS conflict fix: old read lds8[(4jw+c)*132+t] was
//      4-way (banks jw*4 mod 32). New layout: word w of row i stored at
//      col=(w + (i>>2) + (i&3)*8)&31 -> write banks bijective, read banks
//      (wt + jw + 8c)&31 all-distinct. Pure permutation.
// GEMM core (R19): i8 3-plane weights (W = 2^-8*q1 + 2^-15*q2 + 2^-22*q3,
// exact residuals), mfma_i32_16x16x64_i8 fr=lane&15 q=lane>>4, slot swizzle
// phys=row*8+(u0^(row&7)), 512-thr 128m x 64o, kc=128, XCD-aware remap,
// stage->barrier->MFMA->barrier (R20-R22 showed all source-pipelining
// variants regress; 4-block/CU wave overlap already covers the drain).

typedef unsigned short ushort_t;
typedef unsigned int uint_t;
typedef unsigned char uchar_t;
typedef int i32x4 __attribute__((ext_vector_type(4)));

#define S1F 0.00390625f             // 2^-8
#define S2F 3.0517578125e-5f        // 2^-15
#define S3F 2.384185791015625e-7f   // 2^-22

__device__ __forceinline__ void glds16(const uchar_t* g, uchar_t* l) {
  __builtin_amdgcn_global_load_lds(
      (const __attribute__((address_space(1))) uint_t*)g,
      (__attribute__((address_space(3))) uint_t*)l, 16, 0, 0);
}

// ---- prep: W1/W2 -> 3 i8 planes + spike transpose + z3 zero ----------------
__global__ __launch_bounds__(256) void prep(const float* __restrict__ W1,
                                            const float* __restrict__ W2,
                                            const float* __restrict__ spike,
                                            char* __restrict__ w1q1,
                                            char* __restrict__ w1q2,
                                            char* __restrict__ w1q3,
                                            char* __restrict__ w2q1,
                                            char* __restrict__ w2q2,
                                            char* __restrict__ w2q3,
                                            uchar_t* __restrict__ A1,
                                            float* __restrict__ z3) {
  const int tid = threadIdx.x;
  if (blockIdx.x >= 4096) {           // blocks 4096..4099: zero z3 (64 KB)
    float4 z4 = {0.0f, 0.0f, 0.0f, 0.0f};
    float* p = z3 + (size_t)(blockIdx.x - 4096) * 4096 + tid * 16;
#pragma unroll
    for (int i = 0; i < 4; ++i) *(float4*)(p + i * 4) = z4;
    return;
  }
  if (blockIdx.x < 3072) {
    const float* W;
    char *p1, *p2, *p3;
    size_t e0;
    if (blockIdx.x < 2048) {
      W = W1; p1 = w1q1; p2 = w1q2; p3 = w1q3;
      e0 = (size_t)blockIdx.x * 1024 + tid * 4;
    } else {
      W = W2; p1 = w2q1; p2 = w2q2; p3 = w2q3;
      e0 = (size_t)(blockIdx.x - 2048) * 1024 + tid * 4;
    }
    float4 w = *(const float4*)(W + e0);
    char4 c1, c2, c3;
    float q, r;
#define QUANT(comp, f1, f2, f3)                    \
    q = rintf((comp) * 256.0f);  f1 = (char)(int)q; \
    r = (comp) - q * S1F;                           \
    q = rintf(r * 32768.0f);     f2 = (char)(int)q; \
    r = r - q * S2F;                                \
    q = rintf(r * 4194304.0f);   f3 = (char)(int)q;
    QUANT(w.x, c1.x, c2.x, c3.x)
    QUANT(w.y, c1.y, c2.y, c3.y)
    QUANT(w.z, c1.z, c2.z, c3.z)
    QUANT(w.w, c1.w, c2.w, c3.w)
#undef QUANT
    *(char4*)(p1 + e0) = c1;
    *(char4*)(p2 + e0) = c2;
    *(char4*)(p3 + e0) = c3;
    return;
  }
  // spike [b][i][t] f32 -> A1 [b*128+t][i] i8 (0/1); swizzled LDS transpose
  __shared__ uchar_t lds8[128 * 128];  // [i][col] words, col = swizzled t-word
  const int bid = blockIdx.x - 3072;   // 0..1023
  const int b = bid >> 4;
  const int i0 = (bid & 15) * 128;
#pragma unroll
  for (int it = 0; it < 16; ++it) {
    int p = it * 256 + tid;
    int i = p >> 5, w = p & 31;        // w = t-word index (4 t per word)
    float4 v = *(const float4*)(spike + ((size_t)b * 2048 + i0 + i) * 128 + w * 4);
    uint_t pk = (v.x != 0.0f ? 1u : 0u) | (v.y != 0.0f ? 1u : 0u) << 8 |
                (v.z != 0.0f ? 1u : 0u) << 16 | (v.w != 0.0f ? 1u : 0u) << 24;
    int col = (w + (i >> 2) + (i & 3) * 8) & 31;   // bank-bijective swizzle
    *(uint_t*)(lds8 + ((size_t)i * 32 + col) * 4) = pk;
  }
  __syncthreads();
#pragma unroll
  for (int it = 0; it < 16; ++it) {
    int p = it * 256 + tid;
    int t = p >> 5, jw = p & 31;       // output uint (4 i-bytes)
    int wt = t >> 2, tb = t & 3;
    uint_t b0 = lds8[(((4 * jw + 0) * 32) + ((wt + jw + 0) & 31)) * 4 + tb];
    uint_t b1 = lds8[(((4 * jw + 1) * 32) + ((wt + jw + 8) & 31)) * 4 + tb];
    uint_t b2 = lds8[(((4 * jw + 2) * 32) + ((wt + jw + 16) & 31)) * 4 + tb];
    uint_t b3 = lds8[(((4 * jw + 3) * 32) + ((wt + jw + 24) & 31)) * 4 + tb];
    uint_t u = b0 | (b1 << 8) | (b2 << 16) | (b3 << 24);
    *(uint_t*)(A1 + (size_t)(b * 128 + t) * 2048 + i0 + jw * 4) = u;
  }
}

// ---- fused GEMM (128m x 64o, kc=128B, 512 thr, i8 3-plane) + scan ----------
// S != null: write spikes to S (L1). S == null: fused L3 partial-dot path
// (ballot mask -> per-t dot with W3 slice -> atomicAdd z3[j][t][b]).
__global__ __launch_bounds__(512, 4)
void gemm_scan(const uchar_t* __restrict__ A, const char* __restrict__ Q1,
               const char* __restrict__ Q2, const char* __restrict__ Q3,
               uchar_t* __restrict__ S, int K, float* __restrict__ z3,
               const float* __restrict__ W3) {
  __shared__ float smemf[10240];     // 40,960 B staging; Zt overlay 33,280 B
  uchar_t* sA = (uchar_t*)smemf;     // A: slots 0..1023; B plane p: 1024+p*512
  float* Zt = smemf;                 // [128 t][65] epilogue overlay

  const int tid = threadIdx.x;
  const int wave = tid >> 6, lane = tid & 63;
  // XCD-aware remap (grid 16 x 64): XCD ~= bx%8 owns b-tiles [8c, 8c+8)
  const int bt = (blockIdx.x & 7) * 8 + (blockIdx.y & 7);          // 0..63
  const int ot = (blockIdx.x >> 3) * 8 + (blockIdx.y >> 3);        // 0..15
  const int m0 = bt * 128;
  const int o0 = ot * 64;
  const int qm = wave >> 2, qn = wave & 3;
  const int fr = lane & 15, q = lane >> 4;

  i32x4 acc[4][3];
#pragma unroll
  for (int i = 0; i < 4; ++i)
#pragma unroll
    for (int p = 0; p < 3; ++p) acc[i][p] = (i32x4){0, 0, 0, 0};

  // staging: 2560 slots (A 1024 + B 3x512), exactly 5 rounds of 512 threads.
  const char* qplanes[3] = {Q1, Q2, Q3};
  const uchar_t* gsrc[5];
  uchar_t* ldst[5];
#pragma unroll
  for (int it = 0; it < 5; ++it) {
    int s = it * 512 + tid;
    ldst[it] = sA + (size_t)(it * 512 + wave * 64) * 16;
    if (s < 1024) {
      int row = s >> 3;
      int u0 = (s & 7) ^ (row & 7);
      gsrc[it] = A + (size_t)(m0 + row) * K + u0 * 16;
    } else {
      int t2 = s - 1024;
      int p = t2 >> 9, w = t2 & 511;
      int row = w >> 3;
      int u0 = (w & 7) ^ (row & 7);
      gsrc[it] = (const uchar_t*)qplanes[p] + (size_t)(o0 + row) * K + u0 * 16;
    }
  }

  // frag LDS byte offsets per k-half hh: u0 = hh*4 + q
  int aoff[4][2], boff[3][2];  // [p][hh]
#pragma unroll
  for (int i = 0; i < 4; ++i) {
    int row = qm * 64 + i * 16 + fr;
#pragma unroll
    for (int hh = 0; hh < 2; ++hh)
      aoff[i][hh] = (row * 8 + ((hh * 4 + q) ^ (row & 7))) * 16;
  }
  {
    int row = qn * 16 + fr;
#pragma unroll
    for (int hh = 0; hh < 2; ++hh) {
      int rel = row * 8 + ((hh * 4 + q) ^ (row & 7));
#pragma unroll
      for (int p = 0; p < 3; ++p)
        boff[p][hh] = (1024 + p * 512 + rel) * 16;
    }
  }

  for (int kc = 0; kc < K; kc += 128) {
#pragma unroll
    for (int it = 0; it < 5; ++it) glds16(gsrc[it] + kc, ldst[it]);
    __syncthreads();

#pragma unroll
    for (int hh = 0; hh < 2; ++hh) {
      i32x4 af[4], bq[3];
#pragma unroll
      for (int i = 0; i < 4; ++i) af[i] = *(const i32x4*)(sA + aoff[i][hh]);
#pragma unroll
      for (int p = 0; p < 3; ++p) bq[p] = *(const i32x4*)(sA + boff[p][hh]);
#pragma unroll
      for (int p = 0; p < 3; ++p)
#pragma unroll
        for (int i = 0; i < 4; ++i)
          acc[i][p] = __builtin_amdgcn_mfma_i32_16x16x64_i8(af[i], bq[p], acc[i][p], 0, 0, 0);
    }
    __syncthreads();
  }

  // combine planes -> fp32, write Z-tile (C/D: col=fr, row=q*4+rr)
#pragma unroll
  for (int i = 0; i < 4; ++i)
#pragma unroll
    for (int rr = 0; rr < 4; ++rr) {
      int t = qm * 64 + i * 16 + q * 4 + rr;
      float z = (float)acc[i][0][rr] * S1F + (float)acc[i][1][rr] * S2F +
                (float)acc[i][2][rr] * S3F;
      Zt[t * 65 + qn * 16 + fr] = z;
    }
  __syncthreads();

  if (S) {
    // L1: fused leaky-IF scan, write spike plane
    if (tid < 64) {
#pragma clang fp contract(off)
      float cur = 0.0f, vol = 0.0f;
      const int o = o0 + tid;
      for (int t = 0; t < 128; ++t) {
        float z = Zt[t * 65 + tid];
        cur = cur * 0.7f;
        cur = cur + z;
        vol = vol * 0.2f;
        vol = vol + cur;
        float v = vol - 1.0f;
        float s = (v >= 0.0f) ? 1.0f : 0.0f;
        vol = vol * (1.0f - s);
        S[(size_t)(m0 + t) * 1024 + o] = (v >= 0.0f) ? 1u : 0u;
      }
    }
  } else {
    // L2: fused scan + L3 partial dot. masks at float-ofs 8320 (1 KB),
    // W3 slice at 8576 (128 floats) — both beyond Zt's 8320 floats.
    unsigned long long* masks = (unsigned long long*)(smemf + 8320);
    float* w3s = smemf + 8576;
    if (tid < 64) {
#pragma clang fp contract(off)
      float cur = 0.0f, vol = 0.0f;
      for (int t = 0; t < 128; ++t) {
        float z = Zt[t * 65 + tid];
        cur = cur * 0.7f;
        cur = cur + z;
        vol = vol * 0.2f;
        vol = vol + cur;
        float v = vol - 1.0f;
        float s = (v >= 0.0f) ? 1.0f : 0.0f;
        vol = vol * (1.0f - s);
        unsigned long long mk = __ballot(v >= 0.0f);
        if (tid == 0) masks[t] = mk;
      }
    } else if (tid < 192) {
      int r = tid - 64;  // r = j*64 + o
      w3s[r] = W3[(r >> 6) * 1024 + o0 + (r & 63)];
    }
    __syncthreads();
    if (tid < 128) {
      unsigned long long mk = masks[tid];
      float p0 = 0.0f, p1 = 0.0f;
#pragma unroll
      for (int o = 0; o < 64; ++o) {
        float bb = ((mk >> o) & 1ull) ? 1.0f : 0.0f;
        p0 = fmaf(bb, w3s[o], p0);
        p1 = fmaf(bb, w3s[64 + o], p1);
      }
      atomicAdd(z3 + tid * 64 + bt, p0);         // z3[0][t][b]
      atomicAdd(z3 + 8192 + tid * 64 + bt, p1);  // z3[1][t][b]
    }
  }
}

// ---------- final: 128 independent leaky-IF scans over z3 -------------------
__global__ __launch_bounds__(128) void scan3(const float* __restrict__ z3,
                                             float* __restrict__ out) {
#pragma clang fp contract(off)
  const int tid = threadIdx.x;   // b = tid>>1, j = tid&1
  const int b = tid >> 1, j = tid & 1;
  float cur = 0.0f, vol = 0.0f;
  for (int t = 0; t < 128; ++t) {
    float z = z3[j * 8192 + t * 64 + b];
    cur = cur * 0.7f;
    cur = cur + z;
    vol = vol * 0.2f;
    vol = vol + cur;
    float v = vol - 1.0f;
    float s = (v >= 0.0f) ? 1.0f : 0.0f;
    vol = vol * (1.0f - s);
    out[b * 256 + j * 128 + t] = s;
  }
}

extern "C" void kernel_launch(void* const* d_in, const int* in_sizes, int n_in,
                              void* d_out, int out_size, void* d_ws, size_t ws_size,
                              hipStream_t stream) {
  const float* spike = (const float*)d_in[0];  // [64, 2048, 128]
  const float* W1 = (const float*)d_in[1];     // [1024, 2048]
  const float* W2 = (const float*)d_in[2];     // [1024, 1024]
  const float* W3 = (const float*)d_in[3];     // [2, 1024]
  float* out = (float*)d_out;                  // [64, 2, 128]

  char* ws = (char*)d_ws;
  const size_t MB = 1024 * 1024;
  uchar_t* A1 = (uchar_t*)ws;                  // 16 MB [8192][2048] i8
  uchar_t* S2 = (uchar_t*)(ws + 16 * MB);      // 8 MB  [8192][1024] i8
  float* z3 = (float*)(ws + 24 * MB);          // 64 KB [2][128][64] f32
  char* w1q1 = ws + 32 * MB;                   // 2 MB each
  char* w1q2 = ws + 34 * MB;
  char* w1q3 = ws + 36 * MB;
  char* w2q1 = ws + 38 * MB;                   // 1 MB each
  char* w2q2 = ws + 39 * MB;
  char* w2q3 = ws + 40 * MB;

  // blocks 0..2047: W1 quant; 2048..3071: W2 quant; 3072..4095: transpose;
  // 4096..4099: z3 zero
  prep<<<4100, 256, 0, stream>>>(W1, W2, spike, w1q1, w1q2, w1q3, w2q1, w2q2,
                                 w2q3, A1, z3);
  // L1: M=8192 (b*128+t), K=2048 B, O=1024 (16 o-tiles of 64), XCD-remapped
  gemm_scan<<<dim3(16, 64), 512, 0, stream>>>(A1, w1q1, w1q2, w1q3, S2, 2048,
                                              nullptr, nullptr);
  // L2 (+ fused L3 partial dots): K=1024 B, XCD-remapped
  gemm_scan<<<dim3(16, 64), 512, 0, stream>>>(S2, w2q1, w2q2, w2q3, nullptr,
                                              1024, z3, W3);
  // final 128 leaky-IF scans + output
  scan3<<<1, 128, 0, stream>>>(z3, out);
}